// Round 8
// baseline (189.296 us; speedup 1.0000x reference)
//
#include <hip/hip_runtime.h>
#include <stdint.h>

// Fused dynamic-filter network op, bf16 MFMA implicit-GEMM, pipelined.
//   filt[n,oc,h,w] = bc[oc] + sum_{ic,kh,kw} gt_zpad[n,ic,h+kh-1,w+kw-1]*Wc[oc,ic,kh,kw]
//   out[n,c,h,w]   = sum_{k=kh*3+kw} filt[n,c*9+k,h,w] * gr_reppad[n,c,h+kh-1,w+kw-1]
// N=8, C=64, H=W=128, OC=576. filt (302 MB) never materialized.
//
// ws layout:
//   [0, 663552)          Wc bf16, 36 blocks of [144 oc][64 ic], XOR-swizzled,
//                        oc rows PERMUTED: tile row r holds oc (r&15)*9 + (r>>4)
//   [663552, 680192)     16640 B of zeros (OOB row source for conv zero-pad in h)
//   [680192, 17719552)   gt bf16 row-blocks [n][y]: [130 r=w+1][64 ic], swizzled,
//                        r=0 and r=129 are zero rows (conv zero-pad in w)
//
// R17 vs R10 (R11-R16: every schedule permutation landed 88-165us; wall ~=
// MFMA-pipe + LDS-pipe SUMMED, so the lever is LDS TRAFFIC, set by tile shape):
// 4 waves x 8 M-fragments instead of 8 waves x 4 (same M=512 x N=144 block).
//  - Each B fragment now feeds 8 MFMAs instead of 4: per-block LDS reads drop
//    1872 -> 1224 (B 1296->648, A unchanged 576+); LDS pipe 22.5k -> 14.7k cy.
//  - MFMA per SIMD unchanged: 1 wave x 1296 vs 2 x 648. acc doubles to 288
//    regs -> 1 wave/SIMD (__launch_bounds__(256,1), 512-reg budget).
//  - Each wave owns ONE image row: mrow = wv (A slot wave-uniform), epilogue
//    h = h0+wv, w = mf*16+l15.
//  - No SIMD-partner wave: overlap is intra-wave ILP (ds_read in MFMA shadow),
//    no lockstep collisions on the LDS pipe.
// R10's window/barrier schedule, B ring, A-slot recycle, accumulation order,
// and register epilogue are preserved exactly.

typedef short bf16x8 __attribute__((ext_vector_type(8)));
typedef float f32x4 __attribute__((ext_vector_type(4)));

#define ROWBLK_B 16640
#define BTAP_B   18432
#define ZERO_OFF 663552
#define GTB_OFF  (ZERO_OFF + ROWBLK_B)

__device__ __forceinline__ uint32_t f2bf(float f) {
  uint32_t x = __float_as_uint(f);
  return (x + 0x7FFFu + ((x >> 16) & 1u)) >> 16;   // RNE
}

__device__ __forceinline__ void gload_lds16(const void* g, void* l) {
  __builtin_amdgcn_global_load_lds(
      (const __attribute__((address_space(1))) void*)g,
      (__attribute__((address_space(3))) void*)l, 16, 0, 0);
}

// ---- prep 1: Wc [576][64][3][3] f32 -> ws bf16 [tap*4+octile][144][64], pre-swizzled.
// Tile row r holds original oc = octile*144 + (r&15)*9 + (r>>4)  (pi permutation:
// D-row nf*16 + l4*4+q  ->  channel l4*4+q, dyn-tap nf).
__global__ void prep_wc(const float* __restrict__ Wc, uint8_t* __restrict__ ws) {
  int ch = blockIdx.x * 256 + threadIdx.x;   // 41472 x 16B chunks, exact
  int tb = ch / 1152;                        // tap*4 + octile
  int cw = ch - tb * 1152;
  int tap = tb >> 2, octile = tb & 3;
  int row = cw >> 3, sl = cw & 7;
  int slot = sl ^ (row & 7);                 // pre-apply read-side XOR swizzle
  int ic0 = slot * 8;
  int oc = octile * 144 + (row & 15) * 9 + (row >> 4);   // pi permutation
  uint32_t p[4];
#pragma unroll
  for (int e = 0; e < 4; ++e) {
    uint32_t lo = f2bf(Wc[(oc * 64 + ic0 + 2 * e) * 9 + tap]);
    uint32_t hi = f2bf(Wc[(oc * 64 + ic0 + 2 * e + 1) * 9 + tap]);
    p[e] = lo | (hi << 16);
  }
  uint4 u; u.x = p[0]; u.y = p[1]; u.z = p[2]; u.w = p[3];
  *(uint4*)(ws + (size_t)tb * BTAP_B + (size_t)cw * 16) = u;
}

// ---- prep 2: gt [8][64][128][128] f32 -> ws bf16 row-blocks, pre-swizzled, padded
__global__ void prep_gt(const float* __restrict__ gt, uint8_t* __restrict__ ws) {
  int b = blockIdx.x;
  if (b == 1024) {  // zero block for out-of-image rows
    uint4 z; z.x = z.y = z.z = z.w = 0;
    for (int i = threadIdx.x; i < 1040; i += 256)
      *(uint4*)(ws + ZERO_OFF + (size_t)i * 16) = z;
    return;
  }
  int n = b >> 7, y = b & 127;
  uint8_t* base = ws + GTB_OFF + (size_t)b * ROWBLK_B;
  for (int i = threadIdx.x; i < 1040; i += 256) {   // 1040 x 16B chunks per row-block
    int r = i >> 3, sl = i & 7;
    int slot = sl ^ (r & 7);
    uint4 u; u.x = u.y = u.z = u.w = 0;
    if (r >= 1 && r <= 128) {
      int w = r - 1, ic0 = slot * 8;
      uint32_t p[4];
#pragma unroll
      for (int e = 0; e < 4; ++e) {
        uint32_t lo = f2bf(gt[((n * 64 + ic0 + 2 * e) * 128 + y) * 128 + w]);
        uint32_t hi = f2bf(gt[((n * 64 + ic0 + 2 * e + 1) * 128 + y) * 128 + w]);
        p[e] = lo | (hi << 16);
      }
      u.x = p[0]; u.y = p[1]; u.z = p[2]; u.w = p[3];
    }
    *(uint4*)(base + (size_t)i * 16) = u;
  }
}

// ---- main: per block M=512 pixels (4 rows x 128 w) x N=144 oc, K=576
//      4 waves; wave wv owns image row h0+wv, all 128 w (8 M-fragments).
__global__ __launch_bounds__(256, 1) void dfn_mfma(
    const float* __restrict__ gr, const float* __restrict__ bc,
    const uint8_t* __restrict__ ws, float* __restrict__ out) {
  __shared__ uint8_t smem[156928];           // A 5x16640=83200 + B 4x18432=73728
  uint8_t* Abuf = smem;
  uint8_t* Bbuf = smem + 83200;
  const int tid = threadIdx.x;
  const int lane = tid & 63;
  const int wv = tid >> 6;                   // 0..3
  const int l15 = lane & 15;
  const int l4 = lane >> 4;
  // XCD-coscheduling decode: bits[2:0]=nh_low, bits[4:3]=octile, bits[9:5]=nh_high.
  const int bid = blockIdx.x;
  const int octile = (bid >> 3) & 3;
  const int nh = (bid & 7) | ((bid >> 5) << 3);
  const int n = nh >> 5;
  const int h0 = (nh & 31) * 4;

  // ---- precomputed per-lane ds_read offsets (swizzle algebra, zero inner VALU)
  int bo[2], aoff[3][2];
#pragma unroll
  for (int kk = 0; kk < 2; ++kk) {
    bo[kk] = l15 * 128 + ((kk * 64 + l4 * 16) ^ ((l15 & 7) << 4));
#pragma unroll
    for (int dwp = 0; dwp < 3; ++dwp) {
      int rl = l15 + dwp;
      aoff[dwp][kk] = rl * 128 + ((kk * 64 + l4 * 16) ^ ((rl & 7) << 4));
    }
  }

  const uint8_t* gtb = ws + GTB_OFF;
  const uint8_t* zblk = ws + ZERO_OFF;

  // ---- staging with 256 threads: 5 sliced iterations, dst linear per wave
#define ISSUE_B(T, BUFI) do {                                                 \
    const uint8_t* bsrc_ = ws + (size_t)((T) * 4 + octile) * BTAP_B;          \
    uint8_t* bdst_ = Bbuf + (BUFI) * BTAP_B;                                  \
    _Pragma("unroll")                                                         \
    for (int it = 0; it < 5; ++it) {                                          \
      int idx = it * 256 + tid;                                               \
      if (idx < 1152)                                                         \
        gload_lds16(bsrc_ + (size_t)idx * 16,                                 \
                    bdst_ + (size_t)(it * 256 + (tid & ~63)) * 16);           \
    }                                                                         \
  } while (0)

#define ISSUE_AROW(Y, SLOT) do {                                              \
    int y_ = (Y);                                                             \
    const uint8_t* src_ = (y_ >= 0 && y_ < 128)                               \
        ? (gtb + (size_t)(n * 128 + y_) * ROWBLK_B) : zblk;                   \
    uint8_t* dst_ = Abuf + (SLOT) * ROWBLK_B;                                 \
    _Pragma("unroll")                                                         \
    for (int it = 0; it < 5; ++it) {                                          \
      int idx = it * 256 + tid;                                               \
      if (idx < 1040)                                                         \
        gload_lds16(src_ + (size_t)idx * 16,                                  \
                    dst_ + (size_t)(it * 256 + (tid & ~63)) * 16);            \
    }                                                                         \
  } while (0)

  f32x4 acc[8][9];                           // 288 regs: 8 M-frags x 9 taps

// one tap: DH in {-1,0,1}, DWP = dw+1 literal, BUFI = B ring slot.
// Wave-uniform A slot: idx = wv+DH+1 in 0..5 (5 -> slot 0, row h0+4 recycle).
#define TAP(DH, DWP, BUFI) do {                                               \
    const int idxs_ = wv + (DH) + 1;                                          \
    const uint8_t* Arow_ = Abuf + (idxs_ == 5 ? 0 : idxs_) * ROWBLK_B;        \
    const uint8_t* Bcur_ = Bbuf + (BUFI) * BTAP_B;                            \
    _Pragma("unroll")                                                         \
    for (int kk = 0; kk < 2; ++kk) {                                          \
      bf16x8 afr[8];                                                          \
      _Pragma("unroll")                                                       \
      for (int mf = 0; mf < 8; ++mf)                                          \
        afr[mf] = *(const bf16x8*)(Arow_ + mf * 2048 + aoff[DWP][kk]);        \
      const uint8_t* baddr_ = Bcur_ + bo[kk];                                 \
      bf16x8 bq[4];                                                           \
      _Pragma("unroll")                                                       \
      for (int p = 0; p < 4; ++p)                                             \
        bq[p] = *(const bf16x8*)(baddr_ + p * 2048);                          \
      __builtin_amdgcn_s_setprio(1);                                          \
      _Pragma("unroll")                                                       \
      for (int nf = 0; nf < 9; ++nf) {                                        \
        bf16x8 bcur_ = bq[nf & 3];                                            \
        if (nf + 4 < 9)                                                       \
          bq[nf & 3] = *(const bf16x8*)(baddr_ + (nf + 4) * 2048);            \
        _Pragma("unroll")                                                     \
        for (int mf = 0; mf < 8; ++mf)                                        \
          acc[mf][nf] = __builtin_amdgcn_mfma_f32_16x16x32_bf16(              \
              bcur_, afr[mf], acc[mf][nf], 0, 0, 0);                          \
      }                                                                       \
      __builtin_amdgcn_s_setprio(0);                                          \
    }                                                                         \
  } while (0)

  // ---- prologue: A slots 0..4 (rows h0-1 .. h0+3) + B taps 0,1
#pragma unroll
  for (int row = 0; row < 5; ++row) ISSUE_AROW(h0 - 1 + row, row);
  ISSUE_B(0, 0);
  ISSUE_B(1, 1);

  // bias init overlaps the staging loads: acc[mf][nf][q] = bc for
  // oc = octile*144 + (l4*4+q)*9 + nf  (channel l4*4+q, dyn-tap nf)
#pragma unroll
  for (int nf = 0; nf < 9; ++nf) {
#pragma unroll
    for (int q = 0; q < 4; ++q) {
      float bias = bc[octile * 144 + (l4 * 4 + q) * 9 + nf];
#pragma unroll
      for (int mf = 0; mf < 8; ++mf) acc[mf][nf][q] = bias;
    }
  }
  __syncthreads();                            // drain: A(5) + B0,B1 visible

  // ---- window 0: taps 0,1; prefetch taps 2,3
  ISSUE_B(2, 2); ISSUE_B(3, 3);
  TAP(-1, 0, 0); TAP(-1, 1, 1);
  __syncthreads();
  // ---- window 1: taps 2,3; prefetch taps 4,5 (buf0,1 freed by barrier)
  ISSUE_B(4, 0); ISSUE_B(5, 1);
  TAP(-1, 2, 2); TAP(0, 0, 3);
  __syncthreads();
  // ---- window 2: taps 4,5; prefetch 6,7 + A row h0+4 -> slot 0
  //      (slot 0's old row h0-1 last read at tap 2; freed by window-1 barrier)
  ISSUE_B(6, 2); ISSUE_B(7, 3);
  ISSUE_AROW(h0 + 4, 0);
  TAP(0, 1, 0); TAP(0, 2, 1);
  __syncthreads();
  // ---- window 3: taps 6,7; prefetch tap 8
  ISSUE_B(8, 0);
  TAP(1, 0, 2); TAP(1, 1, 3);
  __syncthreads();
  // ---- tap 8; no trailing barrier (epilogue touches no LDS)
  TAP(1, 2, 0);

  // ---- epilogue: register-direct. acc[mf][k][q] = filt(pixel(wv-row, w=
  // mf*16+l15), channel l4*4+q, tap k). Pure VALU + global; no LDS.
  const float* grb = gr + (size_t)(n * 64 + octile * 16 + l4 * 4) * 16384;
  float* outb = out + (size_t)(n * 64 + octile * 16 + l4 * 4) * 16384;
  const int h = h0 + wv;                      // wave-uniform output row
  int yy_[3];
#pragma unroll
  for (int i = 0; i < 3; ++i) {
    int yy = h + i - 1; yy_[i] = (yy < 0 ? 0 : (yy > 127 ? 127 : yy)) * 128;
  }
#pragma unroll
  for (int mf = 0; mf < 8; ++mf) {
    int w = mf * 16 + l15;
    int off[3][3];                            // replicate-clamped, shared over q
#pragma unroll
    for (int i = 0; i < 3; ++i)
#pragma unroll
      for (int j = 0; j < 3; ++j) {
        int xx = w + j - 1; xx = xx < 0 ? 0 : (xx > 127 ? 127 : xx);
        off[i][j] = yy_[i] + xx;
      }
#pragma unroll
    for (int q = 0; q < 4; ++q) {
      const float* grc = grb + (size_t)q * 16384;
      float s = 0.f;
#pragma unroll
      for (int i = 0; i < 3; ++i)
#pragma unroll
        for (int j = 0; j < 3; ++j)
          s = fmaf(acc[mf][i * 3 + j][q], grc[off[i][j]], s);
      outb[(size_t)q * 16384 + h * 128 + w] = s;
    }
  }
}

extern "C" void kernel_launch(void* const* d_in, const int* in_sizes, int n_in,
                              void* d_out, int out_size, void* d_ws, size_t ws_size,
                              hipStream_t stream) {
  const float* gr = (const float*)d_in[0];
  const float* gt = (const float*)d_in[1];
  const float* Wc = (const float*)d_in[2];
  const float* bc = (const float*)d_in[3];
  uint8_t* ws = (uint8_t*)d_ws;
  float* out = (float*)d_out;

  prep_wc<<<162, 256, 0, stream>>>(Wc, ws);
  prep_gt<<<1025, 256, 0, stream>>>(gt, ws);
  dfn_mfma<<<1024, 256, 0, stream>>>(gr, bc, ws, out);
}

// Round 9
// 91.539 us; speedup vs baseline: 2.0679x; 2.0679x over previous
//
#include <hip/hip_runtime.h>
#include <stdint.h>

// Fused dynamic-filter network op, bf16 MFMA implicit-GEMM, pipelined.
//   filt[n,oc,h,w] = bc[oc] + sum_{ic,kh,kw} gt_zpad[n,ic,h+kh-1,w+kw-1]*Wc[oc,ic,kh,kw]
//   out[n,c,h,w]   = sum_{k=kh*3+kw} filt[n,c*9+k,h,w] * gr_reppad[n,c,h+kh-1,w+kw-1]
// N=8, C=64, H=W=128, OC=576. filt (302 MB) never materialized.
//
// ws layout (UNCHANGED from R10):
//   [0, 663552)          Wc bf16, 36 blocks of [144 oc][64 ic], XOR-swizzled,
//                        oc rows PERMUTED: tile row r holds oc (r&15)*9 + (r>>4)
//   [663552, 680192)     16640 B of zeros (OOB row source for conv zero-pad in h)
//   [680192, 17719552)   gt bf16 row-blocks [n][y]: [130 r=w+1][64 ic], swizzled,
//                        r=0 and r=129 are zero rows (conv zero-pad in w)
//
// R18 vs R10 (facts: R10 2-lockstep-waves/SIMD=88.8us; R17 1-wave/SIMD=204us
// -> TLP essential, lockstep is the waste): TWO INDEPENDENT BLOCKS PER CU.
//  - 256-thread blocks (4 waves), M = 4 rows x 64 w, N=144. Per-wave structure
//    identical to R10 (4 M-frags, acc 144, same fragment reads/MFMA counts).
//  - LDS = A 5x8448 + B 2x18432 = 79104 B <= 81920 -> 2 blocks/CU. Each SIMD
//    gets 2 waves from DIFFERENT blocks with independent barrier schedules:
//    structural anti-phasing (R13's goal, no code duplication, no spills).
//  - A tile for w-half wt is a 66-row slice (byte off wt*8192) of the existing
//    130-row gt row-block; 64%8==0 keeps the XOR swizzle slice-invariant ->
//    prep kernels and ws untouched.
//  - B double-buffered, 1-tap windows, 9 __syncthreads (4-wave scope; drains
//    overlap the partner block's compute). A slot-0 recycle as in R10.
// Per-CU pipe demand identical to R10; only wave correlation changes.

typedef short bf16x8 __attribute__((ext_vector_type(8)));
typedef float f32x4 __attribute__((ext_vector_type(4)));

#define ROWBLK_B 16640
#define AROW_B   8448
#define BTAP_B   18432
#define ZERO_OFF 663552
#define GTB_OFF  (ZERO_OFF + ROWBLK_B)

__device__ __forceinline__ uint32_t f2bf(float f) {
  uint32_t x = __float_as_uint(f);
  return (x + 0x7FFFu + ((x >> 16) & 1u)) >> 16;   // RNE
}

__device__ __forceinline__ void gload_lds16(const void* g, void* l) {
  __builtin_amdgcn_global_load_lds(
      (const __attribute__((address_space(1))) void*)g,
      (__attribute__((address_space(3))) void*)l, 16, 0, 0);
}

// ---- prep 1: Wc [576][64][3][3] f32 -> ws bf16 [tap*4+octile][144][64], pre-swizzled.
// Tile row r holds original oc = octile*144 + (r&15)*9 + (r>>4)  (pi permutation:
// D-row nf*16 + l4*4+q  ->  channel l4*4+q, dyn-tap nf).
__global__ void prep_wc(const float* __restrict__ Wc, uint8_t* __restrict__ ws) {
  int ch = blockIdx.x * 256 + threadIdx.x;   // 41472 x 16B chunks, exact
  int tb = ch / 1152;                        // tap*4 + octile
  int cw = ch - tb * 1152;
  int tap = tb >> 2, octile = tb & 3;
  int row = cw >> 3, sl = cw & 7;
  int slot = sl ^ (row & 7);                 // pre-apply read-side XOR swizzle
  int ic0 = slot * 8;
  int oc = octile * 144 + (row & 15) * 9 + (row >> 4);   // pi permutation
  uint32_t p[4];
#pragma unroll
  for (int e = 0; e < 4; ++e) {
    uint32_t lo = f2bf(Wc[(oc * 64 + ic0 + 2 * e) * 9 + tap]);
    uint32_t hi = f2bf(Wc[(oc * 64 + ic0 + 2 * e + 1) * 9 + tap]);
    p[e] = lo | (hi << 16);
  }
  uint4 u; u.x = p[0]; u.y = p[1]; u.z = p[2]; u.w = p[3];
  *(uint4*)(ws + (size_t)tb * BTAP_B + (size_t)cw * 16) = u;
}

// ---- prep 2: gt [8][64][128][128] f32 -> ws bf16 row-blocks, pre-swizzled, padded
__global__ void prep_gt(const float* __restrict__ gt, uint8_t* __restrict__ ws) {
  int b = blockIdx.x;
  if (b == 1024) {  // zero block for out-of-image rows
    uint4 z; z.x = z.y = z.z = z.w = 0;
    for (int i = threadIdx.x; i < 1040; i += 256)
      *(uint4*)(ws + ZERO_OFF + (size_t)i * 16) = z;
    return;
  }
  int n = b >> 7, y = b & 127;
  uint8_t* base = ws + GTB_OFF + (size_t)b * ROWBLK_B;
  for (int i = threadIdx.x; i < 1040; i += 256) {   // 1040 x 16B chunks per row-block
    int r = i >> 3, sl = i & 7;
    int slot = sl ^ (r & 7);
    uint4 u; u.x = u.y = u.z = u.w = 0;
    if (r >= 1 && r <= 128) {
      int w = r - 1, ic0 = slot * 8;
      uint32_t p[4];
#pragma unroll
      for (int e = 0; e < 4; ++e) {
        uint32_t lo = f2bf(gt[((n * 64 + ic0 + 2 * e) * 128 + y) * 128 + w]);
        uint32_t hi = f2bf(gt[((n * 64 + ic0 + 2 * e + 1) * 128 + y) * 128 + w]);
        p[e] = lo | (hi << 16);
      }
      u.x = p[0]; u.y = p[1]; u.z = p[2]; u.w = p[3];
    }
    *(uint4*)(base + (size_t)i * 16) = u;
  }
}

// ---- main: per block M=256 pixels (4 rows x 64 w) x N=144 oc, K=576
//      4 waves; wave wv owns image row h0+wv (4 M-frags of 16 pixels).
//      2 blocks co-resident per CU (LDS 79104 x2 <= 160K).
__global__ __launch_bounds__(256, 2) void dfn_mfma(
    const float* __restrict__ gr, const float* __restrict__ bc,
    const uint8_t* __restrict__ ws, float* __restrict__ out) {
  __shared__ uint8_t smem[79104];            // A 5x8448=42240 + B 2x18432=36864
  uint8_t* Abuf = smem;
  uint8_t* Bbuf = smem + 42240;
  const int tid = threadIdx.x;
  const int lane = tid & 63;
  const int wv = tid >> 6;                   // 0..3
  const int l15 = lane & 15;
  const int l4 = lane >> 4;
  // decode: bits[2:0]=nh_low (XCD spread), [4:3]=octile, [5]=w-half, [10:6]=nh_high
  const int bid = blockIdx.x;
  const int octile = (bid >> 3) & 3;
  const int wt = (bid >> 5) & 1;
  const int nh = (bid & 7) | ((bid >> 6) << 3);
  const int n = nh >> 5;
  const int h0 = (nh & 31) * 4;

  // ---- precomputed per-lane ds_read offsets (swizzle algebra, zero inner VALU)
  int bo[2], aoff[3][2];
#pragma unroll
  for (int kk = 0; kk < 2; ++kk) {
    bo[kk] = l15 * 128 + ((kk * 64 + l4 * 16) ^ ((l15 & 7) << 4));
#pragma unroll
    for (int dwp = 0; dwp < 3; ++dwp) {
      int rl = l15 + dwp;
      aoff[dwp][kk] = rl * 128 + ((kk * 64 + l4 * 16) ^ ((rl & 7) << 4));
    }
  }

  const uint8_t* gtb = ws + GTB_OFF;
  const uint8_t* zblk = ws + ZERO_OFF;

  // B tap tile: 1152 chunks = 4x256 + 128 (last iter half-masked)
#define ISSUE_B(T, BUFI) do {                                                 \
    const uint8_t* bsrc_ = ws + (size_t)((T) * 4 + octile) * BTAP_B;          \
    uint8_t* bdst_ = Bbuf + (BUFI) * BTAP_B;                                  \
    _Pragma("unroll")                                                         \
    for (int it = 0; it < 5; ++it) {                                          \
      int idx = it * 256 + tid;                                               \
      if (idx < 1152)                                                         \
        gload_lds16(bsrc_ + (size_t)idx * 16,                                 \
                    bdst_ + (size_t)(it * 256 + (tid & ~63)) * 16);           \
    }                                                                         \
  } while (0)

  // A row slice: 66 rows x 64 ic = 528 chunks, source slice at wt*8192 inside
  // the 130-row gt row-block (64%8==0 -> swizzle slice-invariant)
#define ISSUE_AROW(Y, SLOT) do {                                              \
    int y_ = (Y);                                                             \
    const uint8_t* src_ = (y_ >= 0 && y_ < 128)                               \
        ? (gtb + (size_t)(n * 128 + y_) * ROWBLK_B + wt * 8192) : zblk;       \
    uint8_t* dst_ = Abuf + (SLOT) * AROW_B;                                   \
    _Pragma("unroll")                                                         \
    for (int it = 0; it < 3; ++it) {                                          \
      int idx = it * 256 + tid;                                               \
      if (idx < 528)                                                          \
        gload_lds16(src_ + (size_t)idx * 16,                                  \
                    dst_ + (size_t)(it * 256 + (tid & ~63)) * 16);            \
    }                                                                         \
  } while (0)

  f32x4 acc[4][9];

// one tap: DH in {-1,0,1}, DWP = dw+1 literal, BUFI = B buffer (0/1).
// Wave-uniform A slot: idx = wv+DH+1 in 0..5 (5 -> slot 0, row h0+4 recycle).
#define TAP(DH, DWP, BUFI) do {                                               \
    const int idxs_ = wv + (DH) + 1;                                          \
    const uint8_t* Arow_ = Abuf + (idxs_ == 5 ? 0 : idxs_) * AROW_B;          \
    const uint8_t* Bcur_ = Bbuf + (BUFI) * BTAP_B;                            \
    _Pragma("unroll")                                                         \
    for (int kk = 0; kk < 2; ++kk) {                                          \
      bf16x8 afr[4];                                                          \
      _Pragma("unroll")                                                       \
      for (int mf = 0; mf < 4; ++mf)                                          \
        afr[mf] = *(const bf16x8*)(Arow_ + mf * 2048 + aoff[DWP][kk]);        \
      const uint8_t* baddr_ = Bcur_ + bo[kk];                                 \
      bf16x8 bq[4];                                                           \
      _Pragma("unroll")                                                       \
      for (int p = 0; p < 4; ++p)                                             \
        bq[p] = *(const bf16x8*)(baddr_ + p * 2048);                          \
      __builtin_amdgcn_s_setprio(1);                                          \
      _Pragma("unroll")                                                       \
      for (int nf = 0; nf < 9; ++nf) {                                        \
        bf16x8 bcur_ = bq[nf & 3];                                            \
        if (nf + 4 < 9)                                                       \
          bq[nf & 3] = *(const bf16x8*)(baddr_ + (nf + 4) * 2048);            \
        _Pragma("unroll")                                                     \
        for (int mf = 0; mf < 4; ++mf)                                        \
          acc[mf][nf] = __builtin_amdgcn_mfma_f32_16x16x32_bf16(              \
              bcur_, afr[mf], acc[mf][nf], 0, 0, 0);                          \
      }                                                                       \
      __builtin_amdgcn_s_setprio(0);                                          \
    }                                                                         \
  } while (0)

  // ---- prologue: A slots 0..4 (rows h0-1 .. h0+3) + B tap 0
#pragma unroll
  for (int row = 0; row < 5; ++row) ISSUE_AROW(h0 - 1 + row, row);
  ISSUE_B(0, 0);

  // bias init overlaps the staging loads: acc[mf][nf][q] = bc for
  // oc = octile*144 + (l4*4+q)*9 + nf  (channel l4*4+q, dyn-tap nf)
#pragma unroll
  for (int nf = 0; nf < 9; ++nf) {
#pragma unroll
    for (int q = 0; q < 4; ++q) {
      float bias = bc[octile * 144 + (l4 * 4 + q) * 9 + nf];
      acc[0][nf][q] = bias; acc[1][nf][q] = bias;
      acc[2][nf][q] = bias; acc[3][nf][q] = bias;
    }
  }
  __syncthreads();                            // A(5) + B0 visible

  // ---- 9 one-tap windows, B double-buffered (tap t in buf t&1):
  // stage B(t+1) while computing tap t; barrier makes it visible and frees
  // buf (t&1) for tap t+2's staging next window.
  ISSUE_B(1, 1); TAP(-1, 0, 0); __syncthreads();
  ISSUE_B(2, 0); TAP(-1, 1, 1); __syncthreads();
  ISSUE_B(3, 1); TAP(-1, 2, 0); __syncthreads();
  // slot 0 (row h0-1): last reader is tap 2 (wave 0) -> freed by the barrier
  // above; restage with row h0+4 (first read at tap 6 by wave 3 as slot "5").
  ISSUE_B(4, 0); ISSUE_AROW(h0 + 4, 0); TAP(0, 0, 1); __syncthreads();
  ISSUE_B(5, 1); TAP(0, 1, 0); __syncthreads();
  ISSUE_B(6, 0); TAP(0, 2, 1); __syncthreads();
  ISSUE_B(7, 1); TAP(1, 0, 0); __syncthreads();
  ISSUE_B(8, 0); TAP(1, 1, 1); __syncthreads();
                 TAP(1, 2, 0);
  // no trailing barrier (epilogue touches no LDS)

  // ---- epilogue: register-direct. acc[mf][k][q] = filt(pixel, channel
  // l4*4+q, tap k); pixel = (row h0+wv, w = wt*64 + mf*16 + l15).
  const float* grb = gr + (size_t)(n * 64 + octile * 16 + l4 * 4) * 16384;
  float* outb = out + (size_t)(n * 64 + octile * 16 + l4 * 4) * 16384;
  const int h = h0 + wv;                      // wave-uniform output row
  int yy_[3];
#pragma unroll
  for (int i = 0; i < 3; ++i) {
    int yy = h + i - 1; yy_[i] = (yy < 0 ? 0 : (yy > 127 ? 127 : yy)) * 128;
  }
#pragma unroll
  for (int mf = 0; mf < 4; ++mf) {
    int w = wt * 64 + mf * 16 + l15;
    int off[3][3];                            // replicate-clamped, shared over q
#pragma unroll
    for (int i = 0; i < 3; ++i)
#pragma unroll
      for (int j = 0; j < 3; ++j) {
        int xx = w + j - 1; xx = xx < 0 ? 0 : (xx > 127 ? 127 : xx);
        off[i][j] = yy_[i] + xx;
      }
#pragma unroll
    for (int q = 0; q < 4; ++q) {
      const float* grc = grb + (size_t)q * 16384;
      float s = 0.f;
#pragma unroll
      for (int i = 0; i < 3; ++i)
#pragma unroll
        for (int j = 0; j < 3; ++j)
          s = fmaf(acc[mf][i * 3 + j][q], grc[off[i][j]], s);
      outb[(size_t)q * 16384 + h * 128 + w] = s;
    }
  }
}

extern "C" void kernel_launch(void* const* d_in, const int* in_sizes, int n_in,
                              void* d_out, int out_size, void* d_ws, size_t ws_size,
                              hipStream_t stream) {
  const float* gr = (const float*)d_in[0];
  const float* gt = (const float*)d_in[1];
  const float* Wc = (const float*)d_in[2];
  const float* bc = (const float*)d_in[3];
  uint8_t* ws = (uint8_t*)d_ws;
  float* out = (float*)d_out;

  prep_wc<<<162, 256, 0, stream>>>(Wc, ws);
  prep_gt<<<1025, 256, 0, stream>>>(gt, ws);
  dfn_mfma<<<2048, 256, 0, stream>>>(gr, bc, ws, out);
}

// Round 10
// 83.745 us; speedup vs baseline: 2.2604x; 1.0931x over previous
//
#include <hip/hip_runtime.h>
#include <stdint.h>

// Fused dynamic-filter network op, bf16 MFMA implicit-GEMM, pipelined.
//   filt[n,oc,h,w] = bc[oc] + sum_{ic,kh,kw} gt_zpad[n,ic,h+kh-1,w+kw-1]*Wc[oc,ic,kh,kw]
//   out[n,c,h,w]   = sum_{k=kh*3+kw} filt[n,c*9+k,h,w] * gr_reppad[n,c,h+kh-1,w+kw-1]
// N=8, C=64, H=W=128, OC=576. filt (302 MB) never materialized.
//
// ws layout (UNCHANGED):
//   [0, 663552)          Wc bf16, 36 blocks of [144 oc][64 ic], XOR-swizzled,
//                        oc rows PERMUTED: tile row r holds oc (r&15)*9 + (r>>4)
//   [663552, 680192)     16640 B of zeros (OOB row source for conv zero-pad in h)
//   [680192, 17719552)   gt bf16 row-blocks [n][y]: [130 r=w+1][64 ic], swizzled,
//                        r=0 and r=129 are zero rows (conv zero-pad in w)
//
// R19 vs R18: dfn_mfma UNTOUCHED (79us, at its additive MFMA+LDS floor).
// Prep path rebuilt (was ~12.5us of the 91.5 total):
//  - prep_gt was ic-major gather: 8 floats/lane at 64KB stride -> ~2x line
//    overfetch (~81MB HBM ~= 12.9us). Now: per-(n,y) block loads gt w-major
//    (float4 coalesced), transposes through LDS (ds_write_b16 with e-rotation
//    so each instr spreads ~8 banks), copies the finished 16640B row-block
//    out with coalesced dwordx4. Traffic 81 -> 49 MB.
//  - prep_wc merged into the same kernel (blocks 1025..1186): one less launch.

typedef short bf16x8 __attribute__((ext_vector_type(8)));
typedef float f32x4 __attribute__((ext_vector_type(4)));

#define ROWBLK_B 16640
#define AROW_B   8448
#define BTAP_B   18432
#define ZERO_OFF 663552
#define GTB_OFF  (ZERO_OFF + ROWBLK_B)

__device__ __forceinline__ uint32_t f2bf(float f) {
  uint32_t x = __float_as_uint(f);
  return (x + 0x7FFFu + ((x >> 16) & 1u)) >> 16;   // RNE
}

__device__ __forceinline__ void gload_lds16(const void* g, void* l) {
  __builtin_amdgcn_global_load_lds(
      (const __attribute__((address_space(1))) void*)g,
      (__attribute__((address_space(3))) void*)l, 16, 0, 0);
}

// ---- merged prep kernel.
// blocks 0..1023:  gt row-block (n = b>>7, y = b&127), coalesced + LDS transpose
// block  1024:     zero block (OOB row source)
// blocks 1025..1186: Wc bf16 pack (pi permutation + XOR swizzle), as before
__global__ void prep(const float* __restrict__ gt, const float* __restrict__ Wc,
                     uint8_t* __restrict__ ws) {
  const int b = blockIdx.x;
  const int tid = threadIdx.x;

  if (b >= 1025) {           // ---- Wc part (162 blocks x 256 threads, exact)
    int ch = (b - 1025) * 256 + tid;         // 41472 x 16B chunks
    int tb = ch / 1152;                      // tap*4 + octile
    int cw = ch - tb * 1152;
    int tap = tb >> 2, octile = tb & 3;
    int row = cw >> 3, sl = cw & 7;
    int slot = sl ^ (row & 7);               // pre-apply read-side XOR swizzle
    int ic0 = slot * 8;
    int oc = octile * 144 + (row & 15) * 9 + (row >> 4);   // pi permutation
    uint32_t p[4];
#pragma unroll
    for (int e = 0; e < 4; ++e) {
      uint32_t lo = f2bf(Wc[(oc * 64 + ic0 + 2 * e) * 9 + tap]);
      uint32_t hi = f2bf(Wc[(oc * 64 + ic0 + 2 * e + 1) * 9 + tap]);
      p[e] = lo | (hi << 16);
    }
    uint4 u; u.x = p[0]; u.y = p[1]; u.z = p[2]; u.w = p[3];
    *(uint4*)(ws + (size_t)tb * BTAP_B + (size_t)cw * 16) = u;
    return;
  }

  if (b == 1024) {           // ---- zero block for out-of-image rows
    uint4 z; z.x = z.y = z.z = z.w = 0;
    for (int i = tid; i < 1040; i += 256)
      *(uint4*)(ws + ZERO_OFF + (size_t)i * 16) = z;
    return;
  }

  // ---- gt row-block: load w-major coalesced, transpose via LDS, copy out.
  __shared__ uint4 lbuf4[1040];              // 16640 B = final row-block image
  uint8_t* lbuf = (uint8_t*)lbuf4;
  const int n = b >> 7, y = b & 127;

  // zero rim rows r=0 (bytes 0..127) and r=129 (bytes 16512..16639)
  if (tid < 16) {
    uint4 z; z.x = z.y = z.z = z.w = 0;
    if (tid < 8) lbuf4[tid] = z;             // row 0: 8 chunks
    else lbuf4[129 * 8 + (tid - 8)] = z;     // row 129: 8 chunks
  }

  // 8 iterations x 256 threads x float4: thread covers (ic = idx>>5, w = 4*(idx&31))
  const float* gtn = gt + (size_t)n * 64 * 16384 + (size_t)y * 128;
#pragma unroll
  for (int it = 0; it < 8; ++it) {
    int idx = it * 256 + tid;
    int ic = idx >> 5;
    int wq = idx & 31;
    float4 v = *(const float4*)(gtn + (size_t)ic * 16384 + wq * 4);
    // write 4 bf16 at rows r = 4wq+1+e, fixed ic; e rotated by wq so each
    // instruction's lanes hit ~8 distinct banks instead of 4.
#pragma unroll
    for (int j = 0; j < 4; ++j) {
      int e = (wq + j) & 3;
      float fe = (e & 2) ? ((e & 1) ? v.w : v.z) : ((e & 1) ? v.y : v.x);
      int r = wq * 4 + 1 + e;
      int sl = (ic >> 3) ^ (r & 7);
      *(uint16_t*)(lbuf + r * 128 + sl * 16 + (ic & 7) * 2) = (uint16_t)f2bf(fe);
    }
  }
  __syncthreads();

  uint8_t* base = ws + GTB_OFF + (size_t)b * ROWBLK_B;
  for (int i = tid; i < 1040; i += 256)
    *(uint4*)(base + (size_t)i * 16) = lbuf4[i];
}

// ---- main: per block M=256 pixels (4 rows x 64 w) x N=144 oc, K=576
//      4 waves; wave wv owns image row h0+wv (4 M-frags of 16 pixels).
//      2 blocks co-resident per CU (LDS 79104 x2 <= 160K).  [R18, unchanged]
__global__ __launch_bounds__(256, 2) void dfn_mfma(
    const float* __restrict__ gr, const float* __restrict__ bc,
    const uint8_t* __restrict__ ws, float* __restrict__ out) {
  __shared__ uint8_t smem[79104];            // A 5x8448=42240 + B 2x18432=36864
  uint8_t* Abuf = smem;
  uint8_t* Bbuf = smem + 42240;
  const int tid = threadIdx.x;
  const int lane = tid & 63;
  const int wv = tid >> 6;                   // 0..3
  const int l15 = lane & 15;
  const int l4 = lane >> 4;
  // decode: bits[2:0]=nh_low (XCD spread), [4:3]=octile, [5]=w-half, [10:6]=nh_high
  const int bid = blockIdx.x;
  const int octile = (bid >> 3) & 3;
  const int wt = (bid >> 5) & 1;
  const int nh = (bid & 7) | ((bid >> 6) << 3);
  const int n = nh >> 5;
  const int h0 = (nh & 31) * 4;

  // ---- precomputed per-lane ds_read offsets (swizzle algebra, zero inner VALU)
  int bo[2], aoff[3][2];
#pragma unroll
  for (int kk = 0; kk < 2; ++kk) {
    bo[kk] = l15 * 128 + ((kk * 64 + l4 * 16) ^ ((l15 & 7) << 4));
#pragma unroll
    for (int dwp = 0; dwp < 3; ++dwp) {
      int rl = l15 + dwp;
      aoff[dwp][kk] = rl * 128 + ((kk * 64 + l4 * 16) ^ ((rl & 7) << 4));
    }
  }

  const uint8_t* gtb = ws + GTB_OFF;
  const uint8_t* zblk = ws + ZERO_OFF;

  // B tap tile: 1152 chunks = 4x256 + 128 (last iter half-masked)
#define ISSUE_B(T, BUFI) do {                                                 \
    const uint8_t* bsrc_ = ws + (size_t)((T) * 4 + octile) * BTAP_B;          \
    uint8_t* bdst_ = Bbuf + (BUFI) * BTAP_B;                                  \
    _Pragma("unroll")                                                         \
    for (int it = 0; it < 5; ++it) {                                          \
      int idx = it * 256 + tid;                                               \
      if (idx < 1152)                                                         \
        gload_lds16(bsrc_ + (size_t)idx * 16,                                 \
                    bdst_ + (size_t)(it * 256 + (tid & ~63)) * 16);           \
    }                                                                         \
  } while (0)

  // A row slice: 66 rows x 64 ic = 528 chunks, source slice at wt*8192 inside
  // the 130-row gt row-block (64%8==0 -> swizzle slice-invariant)
#define ISSUE_AROW(Y, SLOT) do {                                              \
    int y_ = (Y);                                                             \
    const uint8_t* src_ = (y_ >= 0 && y_ < 128)                               \
        ? (gtb + (size_t)(n * 128 + y_) * ROWBLK_B + wt * 8192) : zblk;       \
    uint8_t* dst_ = Abuf + (SLOT) * AROW_B;                                   \
    _Pragma("unroll")                                                         \
    for (int it = 0; it < 3; ++it) {                                          \
      int idx = it * 256 + tid;                                               \
      if (idx < 528)                                                          \
        gload_lds16(src_ + (size_t)idx * 16,                                  \
                    dst_ + (size_t)(it * 256 + (tid & ~63)) * 16);            \
    }                                                                         \
  } while (0)

  f32x4 acc[4][9];

// one tap: DH in {-1,0,1}, DWP = dw+1 literal, BUFI = B buffer (0/1).
// Wave-uniform A slot: idx = wv+DH+1 in 0..5 (5 -> slot 0, row h0+4 recycle).
#define TAP(DH, DWP, BUFI) do {                                               \
    const int idxs_ = wv + (DH) + 1;                                          \
    const uint8_t* Arow_ = Abuf + (idxs_ == 5 ? 0 : idxs_) * AROW_B;          \
    const uint8_t* Bcur_ = Bbuf + (BUFI) * BTAP_B;                            \
    _Pragma("unroll")                                                         \
    for (int kk = 0; kk < 2; ++kk) {                                          \
      bf16x8 afr[4];                                                          \
      _Pragma("unroll")                                                       \
      for (int mf = 0; mf < 4; ++mf)                                          \
        afr[mf] = *(const bf16x8*)(Arow_ + mf * 2048 + aoff[DWP][kk]);        \
      const uint8_t* baddr_ = Bcur_ + bo[kk];                                 \
      bf16x8 bq[4];                                                           \
      _Pragma("unroll")                                                       \
      for (int p = 0; p < 4; ++p)                                             \
        bq[p] = *(const bf16x8*)(baddr_ + p * 2048);                          \
      __builtin_amdgcn_s_setprio(1);                                          \
      _Pragma("unroll")                                                       \
      for (int nf = 0; nf < 9; ++nf) {                                        \
        bf16x8 bcur_ = bq[nf & 3];                                            \
        if (nf + 4 < 9)                                                       \
          bq[nf & 3] = *(const bf16x8*)(baddr_ + (nf + 4) * 2048);            \
        _Pragma("unroll")                                                     \
        for (int mf = 0; mf < 4; ++mf)                                        \
          acc[mf][nf] = __builtin_amdgcn_mfma_f32_16x16x32_bf16(              \
              bcur_, afr[mf], acc[mf][nf], 0, 0, 0);                          \
      }                                                                       \
      __builtin_amdgcn_s_setprio(0);                                          \
    }                                                                         \
  } while (0)

  // ---- prologue: A slots 0..4 (rows h0-1 .. h0+3) + B tap 0
#pragma unroll
  for (int row = 0; row < 5; ++row) ISSUE_AROW(h0 - 1 + row, row);
  ISSUE_B(0, 0);

  // bias init overlaps the staging loads: acc[mf][nf][q] = bc for
  // oc = octile*144 + (l4*4+q)*9 + nf  (channel l4*4+q, dyn-tap nf)
#pragma unroll
  for (int nf = 0; nf < 9; ++nf) {
#pragma unroll
    for (int q = 0; q < 4; ++q) {
      float bias = bc[octile * 144 + (l4 * 4 + q) * 9 + nf];
      acc[0][nf][q] = bias; acc[1][nf][q] = bias;
      acc[2][nf][q] = bias; acc[3][nf][q] = bias;
    }
  }
  __syncthreads();                            // A(5) + B0 visible

  // ---- 9 one-tap windows, B double-buffered (tap t in buf t&1):
  // stage B(t+1) while computing tap t; barrier makes it visible and frees
  // buf (t&1) for tap t+2's staging next window.
  ISSUE_B(1, 1); TAP(-1, 0, 0); __syncthreads();
  ISSUE_B(2, 0); TAP(-1, 1, 1); __syncthreads();
  ISSUE_B(3, 1); TAP(-1, 2, 0); __syncthreads();
  // slot 0 (row h0-1): last reader is tap 2 (wave 0) -> freed by the barrier
  // above; restage with row h0+4 (first read at tap 6 by wave 3 as slot "5").
  ISSUE_B(4, 0); ISSUE_AROW(h0 + 4, 0); TAP(0, 0, 1); __syncthreads();
  ISSUE_B(5, 1); TAP(0, 1, 0); __syncthreads();
  ISSUE_B(6, 0); TAP(0, 2, 1); __syncthreads();
  ISSUE_B(7, 1); TAP(1, 0, 0); __syncthreads();
  ISSUE_B(8, 0); TAP(1, 1, 1); __syncthreads();
                 TAP(1, 2, 0);
  // no trailing barrier (epilogue touches no LDS)

  // ---- epilogue: register-direct. acc[mf][k][q] = filt(pixel, channel
  // l4*4+q, tap k); pixel = (row h0+wv, w = wt*64 + mf*16 + l15).
  const float* grb = gr + (size_t)(n * 64 + octile * 16 + l4 * 4) * 16384;
  float* outb = out + (size_t)(n * 64 + octile * 16 + l4 * 4) * 16384;
  const int h = h0 + wv;                      // wave-uniform output row
  int yy_[3];
#pragma unroll
  for (int i = 0; i < 3; ++i) {
    int yy = h + i - 1; yy_[i] = (yy < 0 ? 0 : (yy > 127 ? 127 : yy)) * 128;
  }
#pragma unroll
  for (int mf = 0; mf < 4; ++mf) {
    int w = wt * 64 + mf * 16 + l15;
    int off[3][3];                            // replicate-clamped, shared over q
#pragma unroll
    for (int i = 0; i < 3; ++i)
#pragma unroll
      for (int j = 0; j < 3; ++j) {
        int xx = w + j - 1; xx = xx < 0 ? 0 : (xx > 127 ? 127 : xx);
        off[i][j] = yy_[i] + xx;
      }
#pragma unroll
    for (int q = 0; q < 4; ++q) {
      const float* grc = grb + (size_t)q * 16384;
      float s = 0.f;
#pragma unroll
      for (int i = 0; i < 3; ++i)
#pragma unroll
        for (int j = 0; j < 3; ++j)
          s = fmaf(acc[mf][i * 3 + j][q], grc[off[i][j]], s);
      outb[(size_t)q * 16384 + h * 128 + w] = s;
    }
  }
}

extern "C" void kernel_launch(void* const* d_in, const int* in_sizes, int n_in,
                              void* d_out, int out_size, void* d_ws, size_t ws_size,
                              hipStream_t stream) {
  const float* gr = (const float*)d_in[0];
  const float* gt = (const float*)d_in[1];
  const float* Wc = (const float*)d_in[2];
  const float* bc = (const float*)d_in[3];
  uint8_t* ws = (uint8_t*)d_ws;
  float* out = (float*)d_out;

  prep<<<1187, 256, 0, stream>>>(gt, Wc, ws);
  dfn_mfma<<<2048, 256, 0, stream>>>(gr, bc, ws, out);
}